// Round 5
// baseline (226.676 us; speedup 1.0000x reference)
//
#include <hip/hip_runtime.h>
#include <math.h>

#define DIM 1024
#define NH 16
#define HD 64
#define TT 2048
#define NTOK 4096   // B*T

typedef __bf16 bf8v __attribute__((ext_vector_type(8)));
typedef float f4v __attribute__((ext_vector_type(4)));
typedef unsigned short us8 __attribute__((ext_vector_type(8)));
typedef unsigned short us4 __attribute__((ext_vector_type(4)));

static __device__ __forceinline__ unsigned short f2bf(float f) {
    unsigned int u = __float_as_uint(f);
    u += 0x7FFFu + ((u >> 16) & 1u);   // RNE
    return (unsigned short)(u >> 16);
}
static __device__ __forceinline__ bf8v ld8(const unsigned short* p) {
    return __builtin_bit_cast(bf8v, *(const us8*)p);
}

// ---------- fused prep: x->bf16 | W transpose->bf16 | rope table ----------
__global__ void k_prep(const float* __restrict__ x, unsigned short* __restrict__ xb,
                       const float* __restrict__ Wq, const float* __restrict__ Wk,
                       const float* __restrict__ Wv, unsigned short* __restrict__ wt,
                       float* __restrict__ rope) {
    int tid = threadIdx.x;
    int bb = blockIdx.x;
    if (bb < 4096) {                       // cast x (4 floats/thread)
        int i = bb * 256 + tid;
        float4 v = ((const float4*)x)[i];
        us4 o;
        o[0] = f2bf(v.x); o[1] = f2bf(v.y); o[2] = f2bf(v.z); o[3] = f2bf(v.w);
        *(us4*)&xb[i * 4] = o;
    } else if (bb < 7168) {                // transpose Wq|Wk|Wv
        __shared__ float tile[32][33];
        bb -= 4096;
        int z = bb >> 10, rem = bb & 1023;
        int bx = rem & 31, by = rem >> 5;
        const float* W = (z == 0) ? Wq : ((z == 1) ? Wk : Wv);
        int tx = tid & 31, ty = tid >> 5;   // (32, 8)
        int c0 = bx * 32, k0 = by * 32;
#pragma unroll
        for (int j = 0; j < 4; j++)
            tile[ty + j * 8][tx] = W[(k0 + ty + j * 8) * DIM + c0 + tx];
        __syncthreads();
        unsigned short* out = wt + z * DIM * DIM;
#pragma unroll
        for (int j = 0; j < 4; j++)
            out[(c0 + ty + j * 8) * DIM + k0 + tx] = f2bf(tile[tx][ty + j * 8]);
    } else {                               // rope [TT][HD]
        int i = (bb - 7168) * 256 + tid;
        int s = i >> 6, d = i & 63;
        float inv = exp2f(-(float)(d & 31) * (13.287712379549449f / 32.0f));
        float a = (float)s * inv;
        rope[i] = (d < 32) ? cosf(a) : sinf(a);
    }
}

// ---------------- R = rope^T rope (64x64), s-parallel x4 ----------------
__global__ void k_R(const float* __restrict__ rope, float* __restrict__ R) {
    __shared__ float red[256];
    int d = blockIdx.x;
    int e = threadIdx.x & 63, sl = threadIdx.x >> 6;
    const float* rp = rope + sl * 512 * 64;
    float acc = 0.f;
    for (int s = 0; s < 512; s++)
        acc += rp[s * 64 + d] * rp[s * 64 + e];
    red[threadIdx.x] = acc;
    __syncthreads();
    if (sl == 0)
        R[d * 64 + e] = (red[e] + red[e + 64]) + (red[e + 128] + red[e + 192]);
}

// ------------- Wo2t[j][r] = sum_e R[d][e] * Wo[h*64+e][j],  r = h*64+d -------------
// grid (16 j-tiles x 16 heads). Coalesced Wo loads via LDS; lanes indexed by d so
// R reads hit consecutive banks and the 2B output stores are contiguous 128B runs.
__global__ void k_wo2(const float* __restrict__ Wo, const float* __restrict__ R,
                      unsigned short* __restrict__ wo2t) {
    __shared__ float Ws[64 * 65];   // Ws[e][j]
    __shared__ float Rt[64 * 65];   // Rt[e][d] = R[d*64+e]
    int tid = threadIdx.x;
    int h = blockIdx.y, j0 = blockIdx.x * 64;
    for (int idx = tid; idx < 4096; idx += 256) {
        int e = idx >> 6, j = idx & 63;
        Ws[e * 65 + j] = Wo[(h * 64 + e) * DIM + j0 + j];
        Rt[e * 65 + j] = R[j * 64 + e];
    }
    __syncthreads();
    int d = tid & 63, jb = (tid >> 6) * 16;
    float acc[16] = {};
    for (int e = 0; e < 64; e++) {
        float r = Rt[e * 65 + d];
#pragma unroll
        for (int jj = 0; jj < 16; jj++)
            acc[jj] += r * Ws[e * 65 + jb + jj];   // wave-uniform addr -> broadcast
    }
#pragma unroll
    for (int jj = 0; jj < 16; jj++)
        wo2t[(j0 + jb + jj) * DIM + h * 64 + d] = f2bf(acc[jj]);
}

// ================= GEMM core: C[M x N] = A[M x 1024] * Bt[N x 1024]^T =================
#define BK 32
#define LDA 40   // BK + 8 pad, keeps 16B row alignment

// QKV projection: N = 3072. Q (pre-scaled by c1), K scatter to [B][H][T][64];
// V TRANSPOSED to [B][H][64][T].
__global__ __launch_bounds__(256, 3) void k_gemm_qkv(const unsigned short* __restrict__ A,
                                                     const unsigned short* __restrict__ Bt,
                                                     unsigned short* __restrict__ qk,
                                                     unsigned short* __restrict__ vt) {
    __shared__ unsigned short As[128 * LDA];
    __shared__ unsigned short Bs[128 * LDA];
    const int K = 1024;
    int tid = threadIdx.x;
    int lane = tid & 63, w = tid >> 6;
    int quad = lane >> 4, l16 = lane & 15;
    int m0 = blockIdx.y * 128, n0 = blockIdx.x * 128;
    int sr = tid >> 1, sc = (tid & 1) * 16;
    const unsigned short* Ag = A + (m0 + sr) * K + sc;
    const unsigned short* Bg = Bt + (n0 + sr) * K + sc;
    int wm = (w >> 1) * 64, wn = (w & 1) * 64;

    us8 a0 = *(const us8*)(Ag);
    us8 a1 = *(const us8*)(Ag + 8);
    us8 b0 = *(const us8*)(Bg);
    us8 b1 = *(const us8*)(Bg + 8);

    f4v acc[4][4] = {};
    for (int k0 = 0; k0 < K; k0 += BK) {
        __syncthreads();
        *(us8*)&As[sr * LDA + sc] = a0;
        *(us8*)&As[sr * LDA + sc + 8] = a1;
        *(us8*)&Bs[sr * LDA + sc] = b0;
        *(us8*)&Bs[sr * LDA + sc + 8] = b1;
        __syncthreads();
        if (k0 + BK < K) {
            a0 = *(const us8*)(Ag + k0 + BK);
            a1 = *(const us8*)(Ag + k0 + BK + 8);
            b0 = *(const us8*)(Bg + k0 + BK);
            b1 = *(const us8*)(Bg + k0 + BK + 8);
        }
        bf8v af[4], bf[4];
#pragma unroll
        for (int mt = 0; mt < 4; mt++)
            af[mt] = ld8(&As[(wm + mt * 16 + l16) * LDA + quad * 8]);
#pragma unroll
        for (int nt = 0; nt < 4; nt++)
            bf[nt] = ld8(&Bs[(wn + nt * 16 + l16) * LDA + quad * 8]);
#pragma unroll
        for (int mt = 0; mt < 4; mt++)
#pragma unroll
            for (int nt = 0; nt < 4; nt++)
                acc[mt][nt] = __builtin_amdgcn_mfma_f32_16x16x32_bf16(af[mt], bf[nt], acc[mt][nt], 0, 0, 0);
    }
#pragma unroll
    for (int mt = 0; mt < 4; mt++) {
#pragma unroll
        for (int nt = 0; nt < 4; nt++) {
            int gc = n0 + wn + nt * 16 + l16;
            int h = (gc >> 6) & 15;
            int d = gc & 63;
            if (gc < 2048) {             // Q or K: [mtx][B][H][T][64]; Q pre-scaled by c1
                float qs = (gc < 1024) ? 0.18033688011111793f : 1.0f;
                int mtx = gc >> 10;
                unsigned short* base = qk + mtx * (NTOK * DIM);
#pragma unroll
                for (int r = 0; r < 4; r++) {
                    int gm = m0 + wm + mt * 16 + quad * 4 + r;
                    int b = gm >> 11, t = gm & 2047;
                    base[((b * NH + h) * TT + t) * HD + d] = f2bf(acc[mt][nt][r] * qs);
                }
            } else {                     // V: transposed [B][H][64][T]
                int gm0 = m0 + wm + mt * 16 + quad * 4;
                int b = gm0 >> 11, t = gm0 & 2047;
                us4 ov;
#pragma unroll
                for (int r = 0; r < 4; r++)
                    ov[r] = f2bf(acc[mt][nt][r]);
                *(us4*)&vt[(((b * NH + h) * HD) + d) * TT + t] = ov;
            }
        }
    }
}

// Output projection: N = 1024, A = attn(bf16 [4096][1024]), + bias, fp32 out
__global__ __launch_bounds__(256, 3) void k_gemm_out(const unsigned short* __restrict__ A,
                                                     const unsigned short* __restrict__ Bt,
                                                     const float* __restrict__ bo,
                                                     float* __restrict__ out) {
    __shared__ unsigned short As[128 * LDA];
    __shared__ unsigned short Bs[128 * LDA];
    const int K = 1024;
    int tid = threadIdx.x;
    int lane = tid & 63, w = tid >> 6;
    int quad = lane >> 4, l16 = lane & 15;
    int m0 = blockIdx.y * 128, n0 = blockIdx.x * 128;
    int sr = tid >> 1, sc = (tid & 1) * 16;
    const unsigned short* Ag = A + (m0 + sr) * K + sc;
    const unsigned short* Bg = Bt + (n0 + sr) * K + sc;
    int wm = (w >> 1) * 64, wn = (w & 1) * 64;

    us8 a0 = *(const us8*)(Ag);
    us8 a1 = *(const us8*)(Ag + 8);
    us8 b0 = *(const us8*)(Bg);
    us8 b1 = *(const us8*)(Bg + 8);

    f4v acc[4][4] = {};
    for (int k0 = 0; k0 < K; k0 += BK) {
        __syncthreads();
        *(us8*)&As[sr * LDA + sc] = a0;
        *(us8*)&As[sr * LDA + sc + 8] = a1;
        *(us8*)&Bs[sr * LDA + sc] = b0;
        *(us8*)&Bs[sr * LDA + sc + 8] = b1;
        __syncthreads();
        if (k0 + BK < K) {
            a0 = *(const us8*)(Ag + k0 + BK);
            a1 = *(const us8*)(Ag + k0 + BK + 8);
            b0 = *(const us8*)(Bg + k0 + BK);
            b1 = *(const us8*)(Bg + k0 + BK + 8);
        }
        bf8v af[4], bf[4];
#pragma unroll
        for (int mt = 0; mt < 4; mt++)
            af[mt] = ld8(&As[(wm + mt * 16 + l16) * LDA + quad * 8]);
#pragma unroll
        for (int nt = 0; nt < 4; nt++)
            bf[nt] = ld8(&Bs[(wn + nt * 16 + l16) * LDA + quad * 8]);
#pragma unroll
        for (int mt = 0; mt < 4; mt++)
#pragma unroll
            for (int nt = 0; nt < 4; nt++)
                acc[mt][nt] = __builtin_amdgcn_mfma_f32_16x16x32_bf16(af[mt], bf[nt], acc[mt][nt], 0, 0, 0);
    }
#pragma unroll
    for (int mt = 0; mt < 4; mt++) {
#pragma unroll
        for (int nt = 0; nt < 4; nt++) {
            int gc = n0 + wn + nt * 16 + l16;
            float bias = bo[gc];
#pragma unroll
            for (int r = 0; r < 4; r++) {
                int gm = m0 + wm + mt * 16 + quad * 4 + r;
                out[gm * DIM + gc] = acc[mt][nt][r] + bias;
            }
        }
    }
}

// ================= flash attention =================
// grid 256 flat (bh = blk&31, qt = blk>>5), 256 threads, 1 block/CU.
// Wave owns 64 q-rows (4 groups of 16): K/V frag reads amortized 2x vs R4
// (616 B LDS traffic per q-row vs 976). kf/vf read once per iter, shared across
// groups. S^T = K·Q^T (Q pre-scaled), O^T = V^T·P^T, lsum via ones-row MFMA.
// P/Q LDS round-trips intra-wave; 2 barriers/iter.
#define LQ 72
__global__ __launch_bounds__(256, 2) void k_flash(const unsigned short* __restrict__ qk,
                                                  const unsigned short* __restrict__ vt,
                                                  unsigned short* __restrict__ attn) {
    __shared__ unsigned short Ks[64 * LQ];    //  9216 B
    __shared__ unsigned short Vs[80 * LQ];    // 11520 B; rows 0-63 V^T, 64 ones, 65-79 zero
    __shared__ unsigned short Ps[256 * LQ];   // 36864 B; [qrow][key], doubles as Q staging
    int tid = threadIdx.x;
    int lane = tid & 63, w = tid >> 6;
    int quad = lane >> 4, l16 = lane & 15;
    int bh = blockIdx.x & 31, qt = blockIdx.x >> 5;
    const unsigned short* Qg = qk + bh * (TT * HD);
    const unsigned short* Kg = qk + NTOK * DIM + bh * (TT * HD);
    const unsigned short* Vtg = vt + bh * (HD * TT);

    // ones/zero rows of Vs (written once)
    for (int idx = tid; idx < 16 * LQ; idx += 256)
        Vs[64 * LQ + idx] = (idx < LQ) ? (unsigned short)0x3F80 : (unsigned short)0;

    {   // stage Q tile (256 x 64) into Ps; thread r stages row r -> intra-wave
        const us8* src = (const us8*)(Qg + (qt * 256 + tid) * HD);
#pragma unroll
        for (int i = 0; i < 8; i++)
            *(us8*)&Ps[tid * LQ + i * 8] = src[i];
    }
    bf8v qf[4][2];   // intra-wave round-trip: no barrier needed
#pragma unroll
    for (int g = 0; g < 4; g++)
#pragma unroll
        for (int ks = 0; ks < 2; ks++)
            qf[g][ks] = ld8(&Ps[(w * 64 + g * 16 + l16) * LQ + ks * 32 + quad * 8]);

    int sr = tid >> 2, sc = (tid & 3) * 16;
    const unsigned short* Kgp = Kg + sr * HD + sc;    // K[key][dim]
    const unsigned short* Vgp = Vtg + sr * TT + sc;   // Vt[dim][key]
    us8 kr0 = *(const us8*)(Kgp);
    us8 kr1 = *(const us8*)(Kgp + 8);
    us8 vr0 = *(const us8*)(Vgp);
    us8 vr1 = *(const us8*)(Vgp + 8);

    f4v oacc[5][4] = {};   // [0..3][g]: O^T dim tiles; [4][g]: ones-row column sums

    for (int it = 0; it < 32; it++) {
        __syncthreads();   // prior-iter Ks/Vs frag reads retired (iter0: ones-init visible)
        *(us8*)&Ks[sr * LQ + sc] = kr0;
        *(us8*)&Ks[sr * LQ + sc + 8] = kr1;
        *(us8*)&Vs[sr * LQ + sc] = vr0;
        *(us8*)&Vs[sr * LQ + sc + 8] = vr1;
        __syncthreads();   // tile visible
        if (it < 31) {     // prefetch next tile during compute
            Kgp += 64 * HD;
            Vgp += 64;
            kr0 = *(const us8*)(Kgp);
            kr1 = *(const us8*)(Kgp + 8);
            vr0 = *(const us8*)(Vgp);
            vr1 = *(const us8*)(Vgp + 8);
        }

        // K frags once, shared across the 4 q-groups
        bf8v kf[2][4];
#pragma unroll
        for (int ks = 0; ks < 2; ks++)
#pragma unroll
            for (int mt = 0; mt < 4; mt++)
                kf[ks][mt] = ld8(&Ks[(mt * 16 + l16) * LQ + ks * 32 + quad * 8]);

        // S^T + softmax, group-sequential (caps sacc register pressure)
#pragma unroll
        for (int g = 0; g < 4; g++) {
            f4v sacc[4] = {};
#pragma unroll
            for (int ks = 0; ks < 2; ks++)
#pragma unroll
                for (int mt = 0; mt < 4; mt++)
                    sacc[mt] = __builtin_amdgcn_mfma_f32_16x16x32_bf16(kf[ks][mt], qf[g][ks], sacc[mt], 0, 0, 0);
#pragma unroll
            for (int mt = 0; mt < 4; mt++) {
                float p0 = __builtin_amdgcn_exp2f(sacc[mt][0]);
                float p1 = __builtin_amdgcn_exp2f(sacc[mt][1]);
                float p2 = __builtin_amdgcn_exp2f(sacc[mt][2]);
                float p3 = __builtin_amdgcn_exp2f(sacc[mt][3]);
                unsigned int d0 = __builtin_amdgcn_perm(__float_as_uint(p1), __float_as_uint(p0), 0x07060302u);
                unsigned int d1 = __builtin_amdgcn_perm(__float_as_uint(p3), __float_as_uint(p2), 0x07060302u);
                uint2 pk; pk.x = d0; pk.y = d1;
                *(uint2*)&Ps[(w * 64 + g * 16 + l16) * LQ + mt * 16 + quad * 4] = pk;
            }
        }

        // O^T += V^T·P^T : vf read once per (ks,mtd), shared across groups
#pragma unroll
        for (int ks = 0; ks < 2; ks++) {
            bf8v pf[4];
#pragma unroll
            for (int g = 0; g < 4; g++)
                pf[g] = ld8(&Ps[(w * 64 + g * 16 + l16) * LQ + ks * 32 + quad * 8]);
#pragma unroll
            for (int mtd = 0; mtd < 5; mtd++) {
                bf8v vf = ld8(&Vs[(mtd * 16 + l16) * LQ + ks * 32 + quad * 8]);
#pragma unroll
                for (int g = 0; g < 4; g++)
                    oacc[mtd][g] = __builtin_amdgcn_mfma_f32_16x16x32_bf16(vf, pf[g], oacc[mtd][g], 0, 0, 0);
            }
        }
    }

    // epilogue: col-q sum lives at lane l16 (quad 0), reg 0 of tile 4
    int b = bh >> 4, h = bh & 15;
#pragma unroll
    for (int g = 0; g < 4; g++) {
        float ssum = __shfl(oacc[4][g][0], l16);
        float inv = 1.0f / ssum;
        int t = qt * 256 + w * 64 + g * 16 + l16;
        unsigned short* dst = attn + (b * TT + t) * DIM + h * HD;
#pragma unroll
        for (int mtd = 0; mtd < 4; mtd++) {
            us4 ov;
#pragma unroll
            for (int r = 0; r < 4; r++)
                ov[r] = f2bf(oacc[mtd][g][r] * inv);
            *(us4*)&dst[mtd * 16 + quad * 4] = ov;
        }
    }
}

extern "C" void kernel_launch(void* const* d_in, const int* in_sizes, int n_in,
                              void* d_out, int out_size, void* d_ws, size_t ws_size,
                              hipStream_t stream) {
    const float* x  = (const float*)d_in[0];
    const float* Wq = (const float*)d_in[1];
    const float* Wk = (const float*)d_in[2];
    const float* Wv = (const float*)d_in[3];
    const float* Wo = (const float*)d_in[4];
    const float* bo = (const float*)d_in[5];
    float* out = (float*)d_out;
    char* ws = (char*)d_ws;

    unsigned short* Xb    = (unsigned short*)(ws);                 //  8 MB
    unsigned short* Wqkvt = (unsigned short*)(ws + 8388608);       //  6 MB
    unsigned short* QK    = (unsigned short*)(ws + 14680064);      // 16 MB (Q then K)
    unsigned short* Vt    = (unsigned short*)(ws + 31457280);      //  8 MB (V transposed)
    unsigned short* attn  = (unsigned short*)(ws + 39845888);      //  8 MB
    unsigned short* Wo2t  = (unsigned short*)(ws + 48234496);      //  2 MB
    float*          rope  = (float*)(ws + 50331648);               // 512 KB
    float*          Rm    = (float*)(ws + 50855936);               // 16 KB

    hipLaunchKernelGGL(k_prep,     dim3(7680),   dim3(256), 0, stream, x, Xb, Wq, Wk, Wv, Wqkvt, rope);
    hipLaunchKernelGGL(k_R,        dim3(64),     dim3(256), 0, stream, rope, Rm);
    hipLaunchKernelGGL(k_wo2,      dim3(16, 16), dim3(256), 0, stream, Wo, Rm, Wo2t);
    hipLaunchKernelGGL(k_gemm_qkv, dim3(24, 32), dim3(256), 0, stream, Xb, Wqkvt, QK, Vt);
    hipLaunchKernelGGL(k_flash,    dim3(256),    dim3(256), 0, stream, QK, Vt, attn);
    hipLaunchKernelGGL(k_gemm_out, dim3(8, 32),  dim3(256), 0, stream, attn, Wo2t, bo, out);
}

// Round 6
// 220.425 us; speedup vs baseline: 1.0284x; 1.0284x over previous
//
#include <hip/hip_runtime.h>
#include <math.h>

#define DIM 1024
#define NH 16
#define HD 64
#define TT 2048
#define NTOK 4096   // B*T

typedef __bf16 bf8v __attribute__((ext_vector_type(8)));
typedef float f4v __attribute__((ext_vector_type(4)));
typedef unsigned short us8 __attribute__((ext_vector_type(8)));
typedef unsigned short us4 __attribute__((ext_vector_type(4)));

static __device__ __forceinline__ unsigned short f2bf(float f) {
    unsigned int u = __float_as_uint(f);
    u += 0x7FFFu + ((u >> 16) & 1u);   // RNE
    return (unsigned short)(u >> 16);
}
static __device__ __forceinline__ bf8v ld8(const unsigned short* p) {
    return __builtin_bit_cast(bf8v, *(const us8*)p);
}
// async global->LDS, 16B per lane; HW dest = wave-uniform base + lane*16
static __device__ __forceinline__ void gl_lds(const unsigned short* g, unsigned short* l) {
    __builtin_amdgcn_global_load_lds((const __attribute__((address_space(1))) unsigned int*)(g),
                                     (__attribute__((address_space(3))) unsigned int*)(l), 16, 0, 0);
}

// ---------- fused prep: x->bf16 | W transpose->bf16 | rope table ----------
__global__ void k_prep(const float* __restrict__ x, unsigned short* __restrict__ xb,
                       const float* __restrict__ Wq, const float* __restrict__ Wk,
                       const float* __restrict__ Wv, unsigned short* __restrict__ wt,
                       float* __restrict__ rope) {
    int tid = threadIdx.x;
    int bb = blockIdx.x;
    if (bb < 4096) {                       // cast x (4 floats/thread)
        int i = bb * 256 + tid;
        float4 v = ((const float4*)x)[i];
        us4 o;
        o[0] = f2bf(v.x); o[1] = f2bf(v.y); o[2] = f2bf(v.z); o[3] = f2bf(v.w);
        *(us4*)&xb[i * 4] = o;
    } else if (bb < 7168) {                // transpose Wq|Wk|Wv
        __shared__ float tile[32][33];
        bb -= 4096;
        int z = bb >> 10, rem = bb & 1023;
        int bx = rem & 31, by = rem >> 5;
        const float* W = (z == 0) ? Wq : ((z == 1) ? Wk : Wv);
        int tx = tid & 31, ty = tid >> 5;   // (32, 8)
        int c0 = bx * 32, k0 = by * 32;
#pragma unroll
        for (int j = 0; j < 4; j++)
            tile[ty + j * 8][tx] = W[(k0 + ty + j * 8) * DIM + c0 + tx];
        __syncthreads();
        unsigned short* out = wt + z * DIM * DIM;
#pragma unroll
        for (int j = 0; j < 4; j++)
            out[(c0 + ty + j * 8) * DIM + k0 + tx] = f2bf(tile[tx][ty + j * 8]);
    } else {                               // rope [TT][HD]
        int i = (bb - 7168) * 256 + tid;
        int s = i >> 6, d = i & 63;
        float inv = exp2f(-(float)(d & 31) * (13.287712379549449f / 32.0f));
        float a = (float)s * inv;
        rope[i] = (d < 32) ? cosf(a) : sinf(a);
    }
}

// ---------------- R = rope^T rope (64x64), s-parallel x4 ----------------
__global__ void k_R(const float* __restrict__ rope, float* __restrict__ R) {
    __shared__ float red[256];
    int d = blockIdx.x;
    int e = threadIdx.x & 63, sl = threadIdx.x >> 6;
    const float* rp = rope + sl * 512 * 64;
    float acc = 0.f;
    for (int s = 0; s < 512; s++)
        acc += rp[s * 64 + d] * rp[s * 64 + e];
    red[threadIdx.x] = acc;
    __syncthreads();
    if (sl == 0)
        R[d * 64 + e] = (red[e] + red[e + 64]) + (red[e + 128] + red[e + 192]);
}

// ------------- Wo2t[j][r] = sum_e R[d][e] * Wo[h*64+e][j],  r = h*64+d -------------
__global__ void k_wo2(const float* __restrict__ Wo, const float* __restrict__ R,
                      unsigned short* __restrict__ wo2t) {
    __shared__ float Ws[64 * 65];   // Ws[e][j]
    __shared__ float Rt[64 * 65];   // Rt[e][d] = R[d*64+e]
    int tid = threadIdx.x;
    int h = blockIdx.y, j0 = blockIdx.x * 64;
    for (int idx = tid; idx < 4096; idx += 256) {
        int e = idx >> 6, j = idx & 63;
        Ws[e * 65 + j] = Wo[(h * 64 + e) * DIM + j0 + j];
        Rt[e * 65 + j] = R[j * 64 + e];
    }
    __syncthreads();
    int d = tid & 63, jb = (tid >> 6) * 16;
    float acc[16] = {};
    for (int e = 0; e < 64; e++) {
        float r = Rt[e * 65 + d];
#pragma unroll
        for (int jj = 0; jj < 16; jj++)
            acc[jj] += r * Ws[e * 65 + jb + jj];
    }
#pragma unroll
    for (int jj = 0; jj < 16; jj++)
        wo2t[(j0 + jb + jj) * DIM + h * 64 + d] = f2bf(acc[jj]);
}

// ================= GEMM core (m97-style): global_load_lds staging, XOR-swizzled LDS =================
// LDS layout: row-major [128][32] bf16, but 16B chunk q of row r stored at phys slot q^(r&3).
// Frag read for logical quarter `quad` uses qx = quad^(l16&3) -> bank-uniform (no >2-way conflicts).

// QKV projection: N = 3072. Q (pre-scaled by c1), K scatter to [B][H][T][64];
// V TRANSPOSED to [B][H][64][T].
__global__ __launch_bounds__(256, 3) void k_gemm_qkv(const unsigned short* __restrict__ A,
                                                     const unsigned short* __restrict__ Bt,
                                                     unsigned short* __restrict__ qk,
                                                     unsigned short* __restrict__ vt) {
    __shared__ unsigned short As[128 * 32];
    __shared__ unsigned short Bs[128 * 32];
    const int K = 1024;
    int tid = threadIdx.x;
    int lane = tid & 63, w = tid >> 6;
    int quad = lane >> 4, l16 = lane & 15;
    int m0 = blockIdx.y * 128, n0 = blockIdx.x * 128;
    int wm = (w >> 1) * 64, wn = (w & 1) * 64;

    // two 16B staging chunks per thread, lane-contiguous per wave
    int s0 = tid, s1 = 256 + tid;
    int r0 = s0 >> 2, cc0 = ((s0 & 3) ^ (r0 & 3)) * 8;
    int r1 = s1 >> 2, cc1 = ((s1 & 3) ^ (r1 & 3)) * 8;
    const unsigned short* Ag0 = A + (m0 + r0) * K + cc0;
    const unsigned short* Ag1 = A + (m0 + r1) * K + cc1;
    const unsigned short* Bg0 = Bt + (n0 + r0) * K + cc0;
    const unsigned short* Bg1 = Bt + (n0 + r1) * K + cc1;
    int qx = quad ^ (l16 & 3);

    f4v acc[4][4] = {};
    for (int k0 = 0; k0 < K; k0 += 32) {
        __syncthreads();                       // prior iter frag reads done
        gl_lds(Ag0 + k0, &As[s0 * 8]);
        gl_lds(Ag1 + k0, &As[s1 * 8]);
        gl_lds(Bg0 + k0, &Bs[s0 * 8]);
        gl_lds(Bg1 + k0, &Bs[s1 * 8]);
        __syncthreads();                       // drains vmcnt -> tiles in LDS
        bf8v af[4], bf[4];
#pragma unroll
        for (int mt = 0; mt < 4; mt++)
            af[mt] = ld8(&As[(wm + mt * 16 + l16) * 32 + qx * 8]);
#pragma unroll
        for (int nt = 0; nt < 4; nt++)
            bf[nt] = ld8(&Bs[(wn + nt * 16 + l16) * 32 + qx * 8]);
#pragma unroll
        for (int mt = 0; mt < 4; mt++)
#pragma unroll
            for (int nt = 0; nt < 4; nt++)
                acc[mt][nt] = __builtin_amdgcn_mfma_f32_16x16x32_bf16(af[mt], bf[nt], acc[mt][nt], 0, 0, 0);
    }
#pragma unroll
    for (int mt = 0; mt < 4; mt++) {
#pragma unroll
        for (int nt = 0; nt < 4; nt++) {
            int gc = n0 + wn + nt * 16 + l16;
            int h = (gc >> 6) & 15;
            int d = gc & 63;
            if (gc < 2048) {             // Q or K: [mtx][B][H][T][64]; Q pre-scaled by c1
                float qs = (gc < 1024) ? 0.18033688011111793f : 1.0f;
                int mtx = gc >> 10;
                unsigned short* base = qk + mtx * (NTOK * DIM);
#pragma unroll
                for (int r = 0; r < 4; r++) {
                    int gm = m0 + wm + mt * 16 + quad * 4 + r;
                    int b = gm >> 11, t = gm & 2047;
                    base[((b * NH + h) * TT + t) * HD + d] = f2bf(acc[mt][nt][r] * qs);
                }
            } else {                     // V: transposed [B][H][64][T]
                int gm0 = m0 + wm + mt * 16 + quad * 4;
                int b = gm0 >> 11, t = gm0 & 2047;
                us4 ov;
#pragma unroll
                for (int r = 0; r < 4; r++)
                    ov[r] = f2bf(acc[mt][nt][r]);
                *(us4*)&vt[(((b * NH + h) * HD) + d) * TT + t] = ov;
            }
        }
    }
}

// Output projection: N = 1024, A = attn(bf16 [4096][1024]), + bias, fp32 out
__global__ __launch_bounds__(256, 3) void k_gemm_out(const unsigned short* __restrict__ A,
                                                     const unsigned short* __restrict__ Bt,
                                                     const float* __restrict__ bo,
                                                     float* __restrict__ out) {
    __shared__ unsigned short As[128 * 32];
    __shared__ unsigned short Bs[128 * 32];
    const int K = 1024;
    int tid = threadIdx.x;
    int lane = tid & 63, w = tid >> 6;
    int quad = lane >> 4, l16 = lane & 15;
    int m0 = blockIdx.y * 128, n0 = blockIdx.x * 128;
    int wm = (w >> 1) * 64, wn = (w & 1) * 64;

    int s0 = tid, s1 = 256 + tid;
    int r0 = s0 >> 2, cc0 = ((s0 & 3) ^ (r0 & 3)) * 8;
    int r1 = s1 >> 2, cc1 = ((s1 & 3) ^ (r1 & 3)) * 8;
    const unsigned short* Ag0 = A + (m0 + r0) * K + cc0;
    const unsigned short* Ag1 = A + (m0 + r1) * K + cc1;
    const unsigned short* Bg0 = Bt + (n0 + r0) * K + cc0;
    const unsigned short* Bg1 = Bt + (n0 + r1) * K + cc1;
    int qx = quad ^ (l16 & 3);

    f4v acc[4][4] = {};
    for (int k0 = 0; k0 < K; k0 += 32) {
        __syncthreads();
        gl_lds(Ag0 + k0, &As[s0 * 8]);
        gl_lds(Ag1 + k0, &As[s1 * 8]);
        gl_lds(Bg0 + k0, &Bs[s0 * 8]);
        gl_lds(Bg1 + k0, &Bs[s1 * 8]);
        __syncthreads();
        bf8v af[4], bf[4];
#pragma unroll
        for (int mt = 0; mt < 4; mt++)
            af[mt] = ld8(&As[(wm + mt * 16 + l16) * 32 + qx * 8]);
#pragma unroll
        for (int nt = 0; nt < 4; nt++)
            bf[nt] = ld8(&Bs[(wn + nt * 16 + l16) * 32 + qx * 8]);
#pragma unroll
        for (int mt = 0; mt < 4; mt++)
#pragma unroll
            for (int nt = 0; nt < 4; nt++)
                acc[mt][nt] = __builtin_amdgcn_mfma_f32_16x16x32_bf16(af[mt], bf[nt], acc[mt][nt], 0, 0, 0);
    }
#pragma unroll
    for (int mt = 0; mt < 4; mt++) {
#pragma unroll
        for (int nt = 0; nt < 4; nt++) {
            int gc = n0 + wn + nt * 16 + l16;
            float bias = bo[gc];
#pragma unroll
            for (int r = 0; r < 4; r++) {
                int gm = m0 + wm + mt * 16 + quad * 4 + r;
                out[gm * DIM + gc] = acc[mt][nt][r] + bias;
            }
        }
    }
}

// ================= flash attention, KV-split x2 =================
// grid 1024: bh = blk&31, split = (blk>>5)&1, qt = blk>>6. R4 wave layout (32 q-rows/wave),
// 16 KV iters per block, 4 blocks/CU. Unnormalized softmax => partials are additive:
// block writes bf16 O-partial + fp32 lsum-partial; k_comb merges.
#define LQ 72
__global__ __launch_bounds__(256, 4) void k_flash(const unsigned short* __restrict__ qk,
                                                  const unsigned short* __restrict__ vt,
                                                  unsigned short* __restrict__ Op,
                                                  float* __restrict__ Ls) {
    __shared__ unsigned short Ks[64 * LQ];
    __shared__ unsigned short Vs[80 * LQ];   // rows 0-63: V^T; row 64: ones; 65-79: zero
    __shared__ unsigned short Ps[128 * LQ];  // [qrow][key]; doubles as Q staging
    int tid = threadIdx.x;
    int lane = tid & 63, w = tid >> 6;
    int quad = lane >> 4, l16 = lane & 15;
    int bh = blockIdx.x & 31;
    int sp = (blockIdx.x >> 5) & 1;
    int qt = blockIdx.x >> 6;
    const unsigned short* Qg = qk + bh * (TT * HD);
    const unsigned short* Kg = qk + NTOK * DIM + bh * (TT * HD);
    const unsigned short* Vtg = vt + bh * (HD * TT);

    // ones/zero rows of Vs (written once)
    for (int idx = tid; idx < 16 * LQ; idx += 256)
        Vs[64 * LQ + idx] = (idx < LQ) ? (unsigned short)0x3F80 : (unsigned short)0;

    {   // stage Q tile (128 x 64) into Ps; row r written by wave r>>5 -> intra-wave
        int r = tid >> 1, c0 = (tid & 1) * 32;
        const us8* src = (const us8*)(Qg + (qt * 128 + r) * HD + c0);
#pragma unroll
        for (int i = 0; i < 4; i++)
            *(us8*)&Ps[r * LQ + c0 + i * 8] = src[i];
    }
    bf8v qf[2][2];   // intra-wave round-trip: no barrier needed
#pragma unroll
    for (int g = 0; g < 2; g++)
#pragma unroll
        for (int ks = 0; ks < 2; ks++)
            qf[g][ks] = ld8(&Ps[(w * 32 + g * 16 + l16) * LQ + ks * 32 + quad * 8]);

    int sr = tid >> 2, sc = (tid & 3) * 16;
    const unsigned short* Kgp = Kg + (sp * 1024 + sr) * HD + sc;    // K[key][dim]
    const unsigned short* Vgp = Vtg + sr * TT + sp * 1024 + sc;     // Vt[dim][key]
    us8 kr0 = *(const us8*)(Kgp);
    us8 kr1 = *(const us8*)(Kgp + 8);
    us8 vr0 = *(const us8*)(Vgp);
    us8 vr1 = *(const us8*)(Vgp + 8);

    f4v oacc[5][2] = {};   // [0..3]: O^T dim tiles; [4]: ones-row column sums

    for (int it = 0; it < 16; it++) {
        __syncthreads();   // prior-iter Ks/Vs reads done (iter0: ones-init visible)
        *(us8*)&Ks[sr * LQ + sc] = kr0;
        *(us8*)&Ks[sr * LQ + sc + 8] = kr1;
        *(us8*)&Vs[sr * LQ + sc] = vr0;
        *(us8*)&Vs[sr * LQ + sc + 8] = vr1;
        __syncthreads();   // tile visible
        if (it < 15) {     // prefetch next tile during compute
            Kgp += 64 * HD;
            Vgp += 64;
            kr0 = *(const us8*)(Kgp);
            kr1 = *(const us8*)(Kgp + 8);
            vr0 = *(const us8*)(Vgp);
            vr1 = *(const us8*)(Vgp + 8);
        }

        // S^T = K·Q^T : 4 key tiles x 2 q-groups, kf shared across groups
        f4v sacc[4][2] = {};
#pragma unroll
        for (int ks = 0; ks < 2; ks++) {
            bf8v kf[4];
#pragma unroll
            for (int mt = 0; mt < 4; mt++)
                kf[mt] = ld8(&Ks[(mt * 16 + l16) * LQ + ks * 32 + quad * 8]);
#pragma unroll
            for (int mt = 0; mt < 4; mt++)
#pragma unroll
                for (int g = 0; g < 2; g++)
                    sacc[mt][g] = __builtin_amdgcn_mfma_f32_16x16x32_bf16(kf[mt], qf[g][ks], sacc[mt][g], 0, 0, 0);
        }

        // p = 2^s (Q pre-scaled); pack via v_perm truncate; intra-wave P write
#pragma unroll
        for (int g = 0; g < 2; g++) {
#pragma unroll
            for (int mt = 0; mt < 4; mt++) {
                float p0 = __builtin_amdgcn_exp2f(sacc[mt][g][0]);
                float p1 = __builtin_amdgcn_exp2f(sacc[mt][g][1]);
                float p2 = __builtin_amdgcn_exp2f(sacc[mt][g][2]);
                float p3 = __builtin_amdgcn_exp2f(sacc[mt][g][3]);
                unsigned int d0 = __builtin_amdgcn_perm(__float_as_uint(p1), __float_as_uint(p0), 0x07060302u);
                unsigned int d1 = __builtin_amdgcn_perm(__float_as_uint(p3), __float_as_uint(p2), 0x07060302u);
                uint2 pk; pk.x = d0; pk.y = d1;
                *(uint2*)&Ps[(w * 32 + g * 16 + l16) * LQ + mt * 16 + quad * 4] = pk;
            }
        }

        // O^T += V^T·P^T (5th dim tile = ones row -> column sums)
#pragma unroll
        for (int ks = 0; ks < 2; ks++) {
            bf8v pf[2];
#pragma unroll
            for (int g = 0; g < 2; g++)
                pf[g] = ld8(&Ps[(w * 32 + g * 16 + l16) * LQ + ks * 32 + quad * 8]);
#pragma unroll
            for (int mtd = 0; mtd < 5; mtd++) {
                bf8v vf = ld8(&Vs[(mtd * 16 + l16) * LQ + ks * 32 + quad * 8]);
#pragma unroll
                for (int g = 0; g < 2; g++)
                    oacc[mtd][g] = __builtin_amdgcn_mfma_f32_16x16x32_bf16(vf, pf[g], oacc[mtd][g], 0, 0, 0);
            }
        }
    }

    // epilogue: write UNNORMALIZED bf16 partial + fp32 lsum partial
    int b = bh >> 4, h = bh & 15;
    unsigned short* Opd = Op + sp * (NTOK * DIM);
#pragma unroll
    for (int g = 0; g < 2; g++) {
        int t = qt * 128 + w * 32 + g * 16 + l16;
        unsigned short* dst = Opd + (b * TT + t) * DIM + h * HD;
#pragma unroll
        for (int mtd = 0; mtd < 4; mtd++) {
            us4 ov;
#pragma unroll
            for (int r = 0; r < 4; r++)
                ov[r] = f2bf(oacc[mtd][g][r]);
            *(us4*)&dst[mtd * 16 + quad * 4] = ov;
        }
        if (quad == 0)
            Ls[sp * 65536 + bh * 2048 + t] = oacc[4][g][0];
    }
}

// ---------------- combine: attn = (Op0 + Op1) / (l0 + l1), bf16 ----------------
__global__ void k_comb(const unsigned short* __restrict__ Op, const float* __restrict__ Ls,
                       unsigned short* __restrict__ attn) {
    int e = (blockIdx.x * 256 + threadIdx.x) * 8;
    int h = (e >> 6) & 15, t = (e >> 10) & 2047, b = e >> 21;
    int bh = b * 16 + h;
    float inv = 1.0f / (Ls[bh * 2048 + t] + Ls[65536 + bh * 2048 + t]);
    us8 a = *(const us8*)&Op[e];
    us8 c = *(const us8*)&Op[NTOK * DIM + e];
    us8 o;
#pragma unroll
    for (int j = 0; j < 8; j++) {
        float fa = __uint_as_float((unsigned int)a[j] << 16);
        float fc = __uint_as_float((unsigned int)c[j] << 16);
        o[j] = f2bf((fa + fc) * inv);
    }
    *(us8*)&attn[e] = o;
}

extern "C" void kernel_launch(void* const* d_in, const int* in_sizes, int n_in,
                              void* d_out, int out_size, void* d_ws, size_t ws_size,
                              hipStream_t stream) {
    const float* x  = (const float*)d_in[0];
    const float* Wq = (const float*)d_in[1];
    const float* Wk = (const float*)d_in[2];
    const float* Wv = (const float*)d_in[3];
    const float* Wo = (const float*)d_in[4];
    const float* bo = (const float*)d_in[5];
    float* out = (float*)d_out;
    char* ws = (char*)d_ws;

    // Op (16MB) aliases Xb+Wqkvt: both are dead after k_gemm_qkv, flash writes Op after.
    unsigned short* Xb    = (unsigned short*)(ws);                 //  8 MB
    unsigned short* Wqkvt = (unsigned short*)(ws + 8388608);       //  6 MB
    unsigned short* Op    = (unsigned short*)(ws);                 // 16 MB (aliases Xb/Wqkvt)
    unsigned short* QK    = (unsigned short*)(ws + 16777216);      // 16 MB (Q then K)
    unsigned short* Vt    = (unsigned short*)(ws + 33554432);      //  8 MB (V transposed)
    unsigned short* attn  = (unsigned short*)(ws + 41943040);      //  8 MB
    unsigned short* Wo2t  = (unsigned short*)(ws + 50331648);      //  2 MB
    float*          rope  = (float*)(ws + 52428800);               // 512 KB
    float*          Rm    = (float*)(ws + 52953088);               // 16 KB
    float*          Ls    = (float*)(ws + 52969472);               // 512 KB

    hipLaunchKernelGGL(k_prep,     dim3(7680),   dim3(256), 0, stream, x, Xb, Wq, Wk, Wv, Wqkvt, rope);
    hipLaunchKernelGGL(k_R,        dim3(64),     dim3(256), 0, stream, rope, Rm);
    hipLaunchKernelGGL(k_wo2,      dim3(16, 16), dim3(256), 0, stream, Wo, Rm, Wo2t);
    hipLaunchKernelGGL(k_gemm_qkv, dim3(24, 32), dim3(256), 0, stream, Xb, Wqkvt, QK, Vt);
    hipLaunchKernelGGL(k_flash,    dim3(1024),   dim3(256), 0, stream, QK, Vt, Op, Ls);
    hipLaunchKernelGGL(k_comb,     dim3(2048),   dim3(256), 0, stream, Op, Ls, attn);
    hipLaunchKernelGGL(k_gemm_out, dim3(8, 32),  dim3(256), 0, stream, attn, Wo2t, bo, out);
}